// Round 1
// baseline (411.186 us; speedup 1.0000x reference)
//
#include <hip/hip_runtime.h>

#define F0 11
#define F1 128
#define F2 64

// ---------------- degree count ----------------
__global__ void k_count(const int* __restrict__ dst, int E, int* __restrict__ cnt) {
    int e = blockIdx.x * blockDim.x + threadIdx.x;
    if (e < E) atomicAdd(&cnt[dst[e]], 1);
}

// dis[n] = 1/sqrt(deg), deg = in_count + 1 (self loop)
__global__ void k_dis(const int* __restrict__ cnt, float* __restrict__ dis, int N) {
    int n = blockIdx.x * blockDim.x + threadIdx.x;
    if (n < N) dis[n] = 1.0f / sqrtf((float)(cnt[n] + 1));
}

// ---------------- layer-1 edge aggregation of RAW x (11 features) ----------------
// agg_x[d][f] += x[s][f] * dis[s]*dis[d]    (16 lanes per edge, 11 active)
__global__ void k_aggx(const int* __restrict__ src, const int* __restrict__ dst,
                       const float* __restrict__ x, const float* __restrict__ dis,
                       float* __restrict__ aggx, int E) {
    int idx = blockIdx.x * blockDim.x + threadIdx.x;
    int e = idx >> 4, f = idx & 15;
    if (e >= E || f >= F0) return;
    int s = src[e], d = dst[e];
    float nrm = dis[s] * dis[d];
    atomicAdd(&aggx[d * F0 + f], x[s * F0 + f] * nrm);
}

// ---------------- h1 = relu((aggx + x*dis^2) @ W1 + b1) ----------------
// one block = 128 threads, 16 nodes per block
__global__ void k_l1(const float* __restrict__ aggx, const float* __restrict__ x,
                     const float* __restrict__ dis, const float* __restrict__ W1,
                     const float* __restrict__ b1, float* __restrict__ h1, int N) {
    __shared__ float sW[F0 * F1];
    __shared__ float sb[F1];
    __shared__ float sa[F0];
    int t = threadIdx.x;
    for (int i = t; i < F0 * F1; i += F1) sW[i] = W1[i];
    sb[t] = b1[t];
    int n0 = blockIdx.x * 16;
    for (int r = 0; r < 16; r++) {
        int n = n0 + r;
        __syncthreads();
        if (n < N && t < F0) {
            float d = dis[n];
            sa[t] = aggx[n * F0 + t] + x[n * F0 + t] * d * d;
        }
        __syncthreads();
        if (n < N) {
            float acc = sb[t];
#pragma unroll
            for (int k = 0; k < F0; k++) acc += sa[k] * sW[k * F1 + t];
            h1[(size_t)n * F1 + t] = fmaxf(acc, 0.0f);
        }
    }
}

// ---------------- t2 = h1 @ W2 ----------------
// block = 256 threads = 4 groups x 64 lanes; 16 nodes per block; W2 in LDS
__global__ void k_l2(const float* __restrict__ h1, const float* __restrict__ W2,
                     float* __restrict__ t2, int N) {
    __shared__ float sW[F1 * F2];   // 32 KB
    __shared__ float sh[4][F1];
    int t = threadIdx.x;
    int grp = t >> 6, lane = t & 63;
    for (int i = t; i < F1 * F2; i += 256) sW[i] = W2[i];
    int n0 = blockIdx.x * 16;
    for (int r = 0; r < 4; r++) {
        int n = n0 + r * 4 + grp;
        __syncthreads();
        if (n < N) {
            sh[grp][lane]      = h1[(size_t)n * F1 + lane];
            sh[grp][lane + 64] = h1[(size_t)n * F1 + lane + 64];
        }
        __syncthreads();
        if (n < N) {
            float acc = 0.0f;
#pragma unroll
            for (int k = 0; k < F1; k++) acc += sh[grp][k] * sW[k * F2 + lane];
            t2[(size_t)n * F2 + lane] = acc;
        }
    }
}

// ---------------- layer-2 edge aggregation (64 features) ----------------
__global__ void k_agg2(const int* __restrict__ src, const int* __restrict__ dst,
                       const float* __restrict__ t2, const float* __restrict__ dis,
                       float* __restrict__ acc2, int E) {
    int idx = blockIdx.x * blockDim.x + threadIdx.x;
    int e = idx >> 6, f = idx & 63;
    if (e >= E) return;
    int s = src[e], d = dst[e];
    float nrm = dis[s] * dis[d];
    atomicAdd(&acc2[d * F2 + f], t2[s * F2 + f] * nrm);
}

// ---------------- h2 = relu(acc2 + t2*dis^2 + b2); mean-pool atomics ----------------
__global__ void k_pool(const float* __restrict__ acc2, const float* __restrict__ t2,
                       const float* __restrict__ dis, const float* __restrict__ b2,
                       const int* __restrict__ batch, float* __restrict__ gsum,
                       float* __restrict__ gcnt, int N) {
    int idx = blockIdx.x * blockDim.x + threadIdx.x;
    int n = idx >> 6, f = idx & 63;
    if (n >= N) return;
    float d = dis[n];
    float h2 = fmaxf(acc2[n * F2 + f] + t2[(size_t)n * F2 + f] * d * d + b2[f], 0.0f);
    int g = batch[n];
    atomicAdd(&gsum[g * F2 + f], h2);
    if (f == 0) atomicAdd(&gcnt[g], 1.0f);
}

// ---------------- per-graph MLP head ----------------
// block = 128 threads, one graph per block
__global__ void k_head(const float* __restrict__ gsum, const float* __restrict__ gcnt,
                       const float* __restrict__ Wf1, const float* __restrict__ bf1,
                       const float* __restrict__ Wf2, const float* __restrict__ bf2,
                       const float* __restrict__ Wf3, const float* __restrict__ bf3,
                       float* __restrict__ out, int G) {
    __shared__ float sg[F2];
    __shared__ float sh1[F1];
    __shared__ float sh2[F2];
    int g = blockIdx.x, t = threadIdx.x;
    if (t < F2) {
        float c = fmaxf(gcnt[g], 1.0f);
        sg[t] = gsum[g * F2 + t] / c;
    }
    __syncthreads();
    // h = relu(g @ Wf1 + bf1), Wf1: [64,128]
    {
        float a = bf1[t];
#pragma unroll 8
        for (int k = 0; k < F2; k++) a += sg[k] * Wf1[k * F1 + t];
        sh1[t] = fmaxf(a, 0.0f);
    }
    __syncthreads();
    if (t < F2) {
        float a = bf2[t];
#pragma unroll 8
        for (int k = 0; k < F1; k++) a += sh1[k] * Wf2[k * F2 + t];
        sh2[t] = fmaxf(a, 0.0f);
    }
    __syncthreads();
    if (t < F2) {
        float v = sh2[t] * Wf3[t];
        for (int off = 32; off > 0; off >>= 1) v += __shfl_down(v, off, 64);
        if (t == 0) out[g] = v + bf3[0];
    }
}

extern "C" void kernel_launch(void* const* d_in, const int* in_sizes, int n_in,
                              void* d_out, int out_size, void* d_ws, size_t ws_size,
                              hipStream_t stream) {
    const float* x     = (const float*)d_in[0];
    const int*   ei    = (const int*)d_in[1];
    const int*   batch = (const int*)d_in[2];
    const float* W1    = (const float*)d_in[3];
    const float* b1    = (const float*)d_in[4];
    const float* W2    = (const float*)d_in[5];
    const float* b2    = (const float*)d_in[6];
    const float* Wf1   = (const float*)d_in[7];
    const float* bf1   = (const float*)d_in[8];
    const float* Wf2   = (const float*)d_in[9];
    const float* bf2   = (const float*)d_in[10];
    const float* Wf3   = (const float*)d_in[11];
    const float* bf3   = (const float*)d_in[12];
    float* out = (float*)d_out;

    const int N = in_sizes[0] / F0;
    const int E = in_sizes[1] / 2;
    const int G = out_size;
    const int* src = ei;          // edge_index[0]
    const int* dst = ei + E;      // edge_index[1]

    // workspace carve-up (256B aligned)
    size_t off = 0;
    auto carve = [&](size_t bytes) {
        void* p = (char*)d_ws + off;
        off += (bytes + 255) & ~(size_t)255;
        return p;
    };
    int*   deg  = (int*)  carve((size_t)N * 4);
    float* dis  = (float*)carve((size_t)N * 4);
    float* aggx = (float*)carve((size_t)N * F0 * 4);
    float* h1   = (float*)carve((size_t)N * F1 * 4);
    float* t2   = (float*)carve((size_t)N * F2 * 4);
    float* acc2 = (float*)carve((size_t)N * F2 * 4);
    float* gsum = (float*)carve((size_t)G * F2 * 4);
    float* gcnt = (float*)carve((size_t)G * 4);
    (void)ws_size; (void)n_in;

    // zero accumulators
    hipMemsetAsync(deg,  0, (size_t)N * 4, stream);
    hipMemsetAsync(aggx, 0, (size_t)N * F0 * 4, stream);
    hipMemsetAsync(acc2, 0, (size_t)N * F2 * 4, stream);
    hipMemsetAsync(gsum, 0, (size_t)G * F2 * 4, stream);
    hipMemsetAsync(gcnt, 0, (size_t)G * 4, stream);

    k_count<<<(E + 255) / 256, 256, 0, stream>>>(dst, E, deg);
    k_dis<<<(N + 255) / 256, 256, 0, stream>>>(deg, dis, N);
    k_aggx<<<(int)(((long long)E * 16 + 255) / 256), 256, 0, stream>>>(src, dst, x, dis, aggx, E);
    k_l1<<<(N + 15) / 16, 128, 0, stream>>>(aggx, x, dis, W1, b1, h1, N);
    k_l2<<<(N + 15) / 16, 256, 0, stream>>>(h1, W2, t2, N);
    k_agg2<<<(int)(((long long)E * 64 + 255) / 256), 256, 0, stream>>>(src, dst, t2, dis, acc2, E);
    k_pool<<<(int)(((long long)N * 64 + 255) / 256), 256, 0, stream>>>(acc2, t2, dis, b2, batch, gsum, gcnt, N);
    k_head<<<G, F1, 0, stream>>>(gsum, gcnt, Wf1, bf1, Wf2, bf2, Wf3, bf3, out, G);
}

// Round 2
// 310.416 us; speedup vs baseline: 1.3246x; 1.3246x over previous
//
#include <hip/hip_runtime.h>

#define F0 11
#define F1 128
#define F2 64

// ---------------- in-degree histogram ----------------
__global__ void k_count(const int* __restrict__ dst, int E, int* __restrict__ cnt) {
    int e = blockIdx.x * blockDim.x + threadIdx.x;
    if (e < E) atomicAdd(&cnt[dst[e]], 1);
}

// ---------------- exclusive scan of deg -> rowptr (3 stages) ----------------
__global__ void k_scanA(const int* __restrict__ deg, int* __restrict__ rowloc,
                        int* __restrict__ bsum, int N) {
    __shared__ int s[256];
    int i = blockIdx.x * 256 + threadIdx.x;
    int v = (i < N) ? deg[i] : 0;
    s[threadIdx.x] = v;
    __syncthreads();
    for (int o = 1; o < 256; o <<= 1) {
        int t = (threadIdx.x >= o) ? s[threadIdx.x - o] : 0;
        __syncthreads();
        s[threadIdx.x] += t;
        __syncthreads();
    }
    if (i < N) rowloc[i] = s[threadIdx.x] - v;  // exclusive within block
    if (threadIdx.x == 255) bsum[blockIdx.x] = s[255];
}

__global__ void k_scanB(int* __restrict__ bsum, int B) {  // single block, B<=256
    __shared__ int s[256];
    int t = threadIdx.x;
    int v = (t < B) ? bsum[t] : 0;
    s[t] = v;
    __syncthreads();
    for (int o = 1; o < 256; o <<= 1) {
        int u = (t >= o) ? s[t - o] : 0;
        __syncthreads();
        s[t] += u;
        __syncthreads();
    }
    if (t < B) bsum[t] = s[t] - v;  // exclusive block offsets
}

// rowptr[i] = rowloc[i] + bsum[block]; also dis = 1/sqrt(deg+1)
__global__ void k_scanC(const int* __restrict__ rowloc, const int* __restrict__ bsum,
                        const int* __restrict__ deg, int* __restrict__ rowptr,
                        float* __restrict__ dis, int N) {
    int i = blockIdx.x * 256 + threadIdx.x;
    if (i < N) {
        rowptr[i] = rowloc[i] + bsum[blockIdx.x];
        dis[i] = 1.0f / sqrtf((float)(deg[i] + 1));
    }
}

// ---------------- scatter edges into CSR (by dst) ----------------
__global__ void k_scatter(const int* __restrict__ src, const int* __restrict__ dst,
                          const int* __restrict__ rowptr, int* __restrict__ fill,
                          int* __restrict__ esrc, int E) {
    int e = blockIdx.x * blockDim.x + threadIdx.x;
    if (e >= E) return;
    int d = dst[e];
    int pos = rowptr[d] + atomicAdd(&fill[d], 1);
    esrc[pos] = src[e];
}

// ---------------- fused layer-1: CSR-aggregate raw x (11f) + @W1 + b1 + relu ----------------
// 256 threads = 4 waves; one node per wave. 16-lane groups each handle one edge.
__global__ void k_agg1l1(const int* __restrict__ rowptr, const int* __restrict__ deg,
                         const int* __restrict__ esrc, const float* __restrict__ x,
                         const float* __restrict__ dis, const float* __restrict__ W1,
                         const float* __restrict__ b1, float* __restrict__ h1, int N) {
    __shared__ float sW[F0 * F1];
    __shared__ float sb[F1];
    int t = threadIdx.x;
    for (int i = t; i < F0 * F1; i += 256) sW[i] = W1[i];
    if (t < F1) sb[t] = b1[t];
    __syncthreads();

    int wid = t >> 6, lane = t & 63;
    int n = blockIdx.x * 4 + wid;
    if (n >= N) return;

    int r0 = rowptr[n], dn_edges = deg[n];
    int eo = lane >> 4, f = lane & 15;

    float acc = 0.0f;
    for (int j = r0 + eo; j < r0 + dn_edges; j += 4) {
        int s = esrc[j];
        float w = dis[s];
        if (f < F0) acc += x[s * F0 + f] * w;
    }
    // reduce over the 4 edge-slots (lanes with same f)
    acc += __shfl_xor(acc, 16, 64);
    acc += __shfl_xor(acc, 32, 64);

    float dn = dis[n];
    float afull = acc * dn;
    if (f < F0) afull += x[n * F0 + f] * dn * dn;  // self-loop term

    // h1[n][t], h1[n][t+64] = relu(a @ W1 + b1)
    float o1 = sb[lane], o2 = sb[lane + 64];
#pragma unroll
    for (int k = 0; k < F0; k++) {
        float ak = __shfl(afull, k, 64);
        o1 += ak * sW[k * F1 + lane];
        o2 += ak * sW[k * F1 + lane + 64];
    }
    h1[(size_t)n * F1 + lane]      = fmaxf(o1, 0.0f);
    h1[(size_t)n * F1 + lane + 64] = fmaxf(o2, 0.0f);
}

// ---------------- t2 = h1 @ W2 ----------------
__global__ void k_l2(const float* __restrict__ h1, const float* __restrict__ W2,
                     float* __restrict__ t2, int N) {
    __shared__ float sW[F1 * F2];   // 32 KB
    __shared__ float sh[4][F1];
    int t = threadIdx.x;
    int grp = t >> 6, lane = t & 63;
    for (int i = t; i < F1 * F2; i += 256) sW[i] = W2[i];
    int n0 = blockIdx.x * 16;
    for (int r = 0; r < 4; r++) {
        int n = n0 + r * 4 + grp;
        __syncthreads();
        if (n < N) {
            sh[grp][lane]      = h1[(size_t)n * F1 + lane];
            sh[grp][lane + 64] = h1[(size_t)n * F1 + lane + 64];
        }
        __syncthreads();
        if (n < N) {
            float acc = 0.0f;
#pragma unroll
            for (int k = 0; k < F1; k++) acc += sh[grp][k] * sW[k * F2 + lane];
            t2[(size_t)n * F2 + lane] = acc;
        }
    }
}

// ---------------- fused layer-2 aggregate (CSR gather) + relu + mean-pool atomics ----------------
// 256 threads = 4 waves; one node per wave; lane = feature.
__global__ void k_agg2pool(const int* __restrict__ rowptr, const int* __restrict__ deg,
                           const int* __restrict__ esrc, const float* __restrict__ t2,
                           const float* __restrict__ dis, const float* __restrict__ b2,
                           const int* __restrict__ batch, float* __restrict__ gsum,
                           float* __restrict__ gcnt, int N) {
    int t = threadIdx.x;
    int wid = t >> 6, lane = t & 63;
    int n = blockIdx.x * 4 + wid;
    if (n >= N) return;

    int r0 = rowptr[n], r1 = r0 + deg[n];
    float acc = 0.0f;
    for (int base = r0; base < r1; base += 64) {
        int m = min(64, r1 - base);
        int sidx = 0; float wdis = 0.0f;
        if (lane < m) {
            sidx = esrc[base + lane];
            wdis = dis[sidx];
        }
        for (int j = 0; j < m; j++) {
            int s   = __shfl(sidx, j, 64);
            float w = __shfl(wdis, j, 64);
            acc += w * t2[(size_t)s * F2 + lane];
        }
    }
    float dn = dis[n];
    float h2 = fmaxf(acc * dn + t2[(size_t)n * F2 + lane] * dn * dn + b2[lane], 0.0f);
    int g = batch[n];
    atomicAdd(&gsum[g * F2 + lane], h2);
    if (lane == 0) atomicAdd(&gcnt[g], 1.0f);
}

// ---------------- per-graph MLP head ----------------
__global__ void k_head(const float* __restrict__ gsum, const float* __restrict__ gcnt,
                       const float* __restrict__ Wf1, const float* __restrict__ bf1,
                       const float* __restrict__ Wf2, const float* __restrict__ bf2,
                       const float* __restrict__ Wf3, const float* __restrict__ bf3,
                       float* __restrict__ out, int G) {
    __shared__ float sg[F2];
    __shared__ float sh1[F1];
    __shared__ float sh2[F2];
    int g = blockIdx.x, t = threadIdx.x;
    if (t < F2) {
        float c = fmaxf(gcnt[g], 1.0f);
        sg[t] = gsum[g * F2 + t] / c;
    }
    __syncthreads();
    {
        float a = bf1[t];
#pragma unroll 8
        for (int k = 0; k < F2; k++) a += sg[k] * Wf1[k * F1 + t];
        sh1[t] = fmaxf(a, 0.0f);
    }
    __syncthreads();
    if (t < F2) {
        float a = bf2[t];
#pragma unroll 8
        for (int k = 0; k < F1; k++) a += sh1[k] * Wf2[k * F2 + t];
        sh2[t] = fmaxf(a, 0.0f);
    }
    __syncthreads();
    if (t < F2) {
        float v = sh2[t] * Wf3[t];
        for (int off = 32; off > 0; off >>= 1) v += __shfl_down(v, off, 64);
        if (t == 0) out[g] = v + bf3[0];
    }
}

extern "C" void kernel_launch(void* const* d_in, const int* in_sizes, int n_in,
                              void* d_out, int out_size, void* d_ws, size_t ws_size,
                              hipStream_t stream) {
    const float* x     = (const float*)d_in[0];
    const int*   ei    = (const int*)d_in[1];
    const int*   batch = (const int*)d_in[2];
    const float* W1    = (const float*)d_in[3];
    const float* b1    = (const float*)d_in[4];
    const float* W2    = (const float*)d_in[5];
    const float* b2    = (const float*)d_in[6];
    const float* Wf1   = (const float*)d_in[7];
    const float* bf1   = (const float*)d_in[8];
    const float* Wf2   = (const float*)d_in[9];
    const float* bf2   = (const float*)d_in[10];
    const float* Wf3   = (const float*)d_in[11];
    const float* bf3   = (const float*)d_in[12];
    float* out = (float*)d_out;

    const int N = in_sizes[0] / F0;
    const int E = in_sizes[1] / 2;
    const int G = out_size;
    const int* src = ei;          // edge_index[0]
    const int* dst = ei + E;      // edge_index[1]

    size_t off = 0;
    auto carve = [&](size_t bytes) {
        void* p = (char*)d_ws + off;
        off += (bytes + 255) & ~(size_t)255;
        return p;
    };
    int*   deg    = (int*)  carve((size_t)N * 4);
    int*   rowloc = (int*)  carve((size_t)N * 4);
    int*   rowptr = (int*)  carve((size_t)N * 4);
    int*   fill   = (int*)  carve((size_t)N * 4);
    int*   bsum   = (int*)  carve(256 * 4);
    float* dis    = (float*)carve((size_t)N * 4);
    int*   esrc   = (int*)  carve((size_t)E * 4);
    float* h1     = (float*)carve((size_t)N * F1 * 4);
    float* t2     = (float*)carve((size_t)N * F2 * 4);
    float* gsum   = (float*)carve((size_t)G * F2 * 4);
    float* gcnt   = (float*)carve((size_t)G * 4);
    (void)ws_size; (void)n_in;

    const int NB = (N + 255) / 256;  // scan blocks (<=256 required)

    hipMemsetAsync(deg,  0, (size_t)N * 4, stream);
    hipMemsetAsync(fill, 0, (size_t)N * 4, stream);
    hipMemsetAsync(gsum, 0, (size_t)G * F2 * 4, stream);
    hipMemsetAsync(gcnt, 0, (size_t)G * 4, stream);

    k_count  <<<(E + 255) / 256, 256, 0, stream>>>(dst, E, deg);
    k_scanA  <<<NB, 256, 0, stream>>>(deg, rowloc, bsum, N);
    k_scanB  <<<1, 256, 0, stream>>>(bsum, NB);
    k_scanC  <<<NB, 256, 0, stream>>>(rowloc, bsum, deg, rowptr, dis, N);
    k_scatter<<<(E + 255) / 256, 256, 0, stream>>>(src, dst, rowptr, fill, esrc, E);
    k_agg1l1 <<<(N + 3) / 4, 256, 0, stream>>>(rowptr, deg, esrc, x, dis, W1, b1, h1, N);
    k_l2     <<<(N + 15) / 16, 256, 0, stream>>>(h1, W2, t2, N);
    k_agg2pool<<<(N + 3) / 4, 256, 0, stream>>>(rowptr, deg, esrc, t2, dis, b2, batch, gsum, gcnt, N);
    k_head   <<<G, F1, 0, stream>>>(gsum, gcnt, Wf1, bf1, Wf2, bf2, Wf3, bf3, out, G);
}